// Round 23
// baseline (167.202 us; speedup 1.0000x reference)
//
#include <hip/hip_runtime.h>
#include <hip/hip_bf16.h>
#include <hip/hip_fp16.h>

#define N_NODES 50000
#define N_EDGES 1600000
#define IN_F 128
#define OUT_F 32
#define HEADS 4
#define NEG_SLOPE 0.2f
#define HO (HEADS * OUT_F)

#define NBUCKET 1563                           // ceil(N_NODES / 32)
#define BBLK 256                               // histogram/scatter blocks
#define EPB (N_EDGES / BBLK)                   // 6250 edges per block
#define PROJ_BLOCKS ((N_NODES + 63) / 64)      // 782
#define PROJ_A 282                             // paired with colscan (~10us)
#define PROJ_B (PROJ_BLOCKS - PROJ_A)          // 500, paired with scatter
#define SCAN_BLKS ((NBUCKET + 255) / 256)      // 7
#define AGG_BLOCKS 3125
#define AGG_WAVES (AGG_BLOCKS * 4)
#define WPITCH 136                             // bf16 pitch (17 x b128)
#define BCAP 2048                              // max records per bucket (LDS)

typedef __attribute__((ext_vector_type(8))) short bf16x8;
typedef __attribute__((ext_vector_type(4))) float f32x4;

__device__ __forceinline__ unsigned short bf16_bits(float f) {
    union { __hip_bfloat16 b; unsigned short u; } cv;
    cv.b = __float2bfloat16(f);
    return cv.u;
}
__device__ __forceinline__ unsigned short f16_bits(float f) {
    union { __half h; unsigned short u; } cv;
    cv.h = __float2half(f);
    return cv.u;
}
__device__ __forceinline__ float f16u(unsigned short u) {
    union { unsigned short x; __half h; } cv;
    cv.x = u;
    return __half2float(cv.h);
}

// ---- shared proj body (node tile pb: 64 nodes x 128 cols, K=128) ----
__device__ __forceinline__ void proj_body(
    int pb, int t, unsigned short* xls, unsigned short* wls,
    const float* __restrict__ x, const unsigned short* __restrict__ Wtg,
    const float* __restrict__ a_src, const float* __restrict__ a_dst,
    unsigned short* __restrict__ h_u16, float* __restrict__ attn_s4,
    float* __restrict__ attn_d4)
{
    const int base = pb * 64;
    {   // stage Wt (flat copy, already padded): 2176 uint4
        const uint4* src = (const uint4*)Wtg;
        uint4* dst = (uint4*)wls;
        for (int i = t; i < 2176; i += 256) dst[i] = src[i];
    }
    {   // stage x tile: 64 rows x 32 float4, convert to bf16
        const float4* xsrc = (const float4*)x + (size_t)base * 32;
        #pragma unroll
        for (int i = 0; i < 8; ++i) {
            const int idx = t + i * 256;           // 0..2047
            const int row = idx >> 5;
            const int c4 = idx & 31;
            float4 v = {0.f, 0.f, 0.f, 0.f};
            if (base + row < N_NODES) v = xsrc[row * 32 + c4];
            ushort4 o;
            o.x = bf16_bits(v.x); o.y = bf16_bits(v.y);
            o.z = bf16_bits(v.z); o.w = bf16_bits(v.w);
            *(ushort4*)&xls[row * WPITCH + c4 * 4] = o;
        }
    }
    __syncthreads();

    const int w = t >> 6;                          // m-tile 0..3
    const int lane = t & 63;
    const int lr = lane & 15;                      // A-row / B-col
    const int lq = lane >> 4;                      // k-quadrant

    const unsigned short* ap = &xls[(w * 16 + lr) * WPITCH + lq * 8];
    const unsigned short* bp = &wls[lr * WPITCH + lq * 8];

    f32x4 acc[8];
    #pragma unroll
    for (int ct = 0; ct < 8; ++ct) acc[ct] = (f32x4){0.f, 0.f, 0.f, 0.f};

    #pragma unroll
    for (int ks = 0; ks < 4; ++ks) {
        const bf16x8 a = *(const bf16x8*)(ap + ks * 32);
        #pragma unroll
        for (int ct = 0; ct < 8; ++ct) {
            const bf16x8 bv = *(const bf16x8*)(bp + ct * 16 * WPITCH + ks * 32);
            acc[ct] = __builtin_amdgcn_mfma_f32_16x16x32_bf16(a, bv, acc[ct], 0, 0, 0);
        }
    }

    const int nodeq = base + w * 16 + lq * 4;
    #pragma unroll
    for (int r = 0; r < 4; ++r) {
        const int node = nodeq + r;
        if (node >= N_NODES) continue;
        unsigned short* hrow = h_u16 + (size_t)node * 128 + lr;
        #pragma unroll
        for (int ct = 0; ct < 8; ++ct)
            hrow[ct * 16] = bf16_bits(acc[ct][r]);
    }

    float asv[8], adv[8];
    #pragma unroll
    for (int h = 0; h < 4; ++h) {
        asv[2 * h]     = a_src[32 * h + lr];
        asv[2 * h + 1] = a_src[32 * h + 16 + lr];
        adv[2 * h]     = a_dst[32 * h + lr];
        adv[2 * h + 1] = a_dst[32 * h + 16 + lr];
    }
    #pragma unroll
    for (int h = 0; h < 4; ++h) {
        #pragma unroll
        for (int r = 0; r < 4; ++r) {
            float ps = acc[2 * h][r] * asv[2 * h] + acc[2 * h + 1][r] * asv[2 * h + 1];
            float pd = acc[2 * h][r] * adv[2 * h] + acc[2 * h + 1][r] * adv[2 * h + 1];
            #pragma unroll
            for (int m = 8; m >= 1; m >>= 1) {
                ps += __shfl_xor(ps, m);
                pd += __shfl_xor(pd, m);
            }
            const int node = nodeq + r;
            if (lr == 0 && node < N_NODES) {
                attn_s4[node * HEADS + h] = ps;
                attn_d4[node * HEADS + h] = pd;
            }
        }
    }
}

// K1: blocks [0,256): per-block LDS histogram over 1563 coarse buckets
//     (dst>>5), 1024 threads. blocks [256,264): W -> Wtg bf16 transpose.
__global__ __launch_bounds__(1024) void k_bhist(
    const int* __restrict__ ei, int* __restrict__ bhist,
    const float* __restrict__ W, unsigned short* __restrict__ Wtg)
{
    const int blk = blockIdx.x;
    const int t = threadIdx.x;
    if (blk >= BBLK) {                          // W prep
        const int bp = blk - BBLK;
        #pragma unroll
        for (int i = 0; i < 2; ++i) {
            const int idx = bp * 2048 + t + i * 1024;  // 16384 f32 total
            const int h = idx >> 12;
            const int k = (idx >> 5) & 127;
            const int o = idx & 31;
            Wtg[(size_t)(h * 32 + o) * WPITCH + k] = bf16_bits(W[idx]);
        }
        return;
    }
    __shared__ int lhist[NBUCKET];
    for (int i = t; i < NBUCKET; i += 1024) lhist[i] = 0;
    __syncthreads();
    const int* dstp = ei + N_EDGES + blk * EPB;
    for (int i = t; i < EPB; i += 1024)
        atomicAdd(&lhist[dstp[i] >> 5], 1);
    __syncthreads();
    int* dump = bhist + (size_t)blk * NBUCKET;
    for (int i = t; i < NBUCKET; i += 1024) dump[i] = lhist[i];
}

// K2: proj first part (nodes [0, 282*64)) ∥ bhist column-scan.
__global__ __launch_bounds__(256, 2) void k_projA_scan(
    const float* __restrict__ x, const unsigned short* __restrict__ Wtg,
    const float* __restrict__ a_src, const float* __restrict__ a_dst,
    unsigned short* __restrict__ h_u16, float* __restrict__ attn_s4,
    float* __restrict__ attn_d4, int* __restrict__ bhist,
    int* __restrict__ btotal)
{
    __shared__ unsigned short xls[64 * WPITCH];    // 17408 B
    __shared__ unsigned short wls[128 * WPITCH];   // 34816 B
    const int t = threadIdx.x;

    if (blockIdx.x < SCAN_BLKS) {
        const int j = blockIdx.x * 256 + t;
        if (j >= NBUCKET) return;
        int run = 0;
        for (int blk = 0; blk < BBLK; blk += 8) {
            int v[8];
            #pragma unroll
            for (int q = 0; q < 8; ++q)
                v[q] = bhist[(size_t)(blk + q) * NBUCKET + j];
            #pragma unroll
            for (int q = 0; q < 8; ++q) {
                const int nv = v[q];
                bhist[(size_t)(blk + q) * NBUCKET + j] = run;
                run += nv;
            }
        }
        btotal[j] = run;
        return;
    }
    proj_body(blockIdx.x - SCAN_BLKS, t, xls, wls,
              x, Wtg, a_src, a_dst, h_u16, attn_s4, attn_d4);
}

// K3: exclusive scan of bucket totals -> bbase (single block)
__global__ __launch_bounds__(256) void k_bbase(
    const int* __restrict__ btotal, int* __restrict__ bbase,
    int* __restrict__ offsets)
{
    __shared__ int part[256];
    const int t = threadIdx.x;
    const int CH = 7;                              // 7*256 >= 1563
    const int lo = t * CH;
    const int hi = min(lo + CH, NBUCKET);
    int s = 0;
    for (int i = lo; i < hi; ++i) s += btotal[i];
    part[t] = s;
    __syncthreads();
    for (int d = 1; d < 256; d <<= 1) {
        const int v = (t >= d) ? part[t - d] : 0;
        __syncthreads();
        part[t] += v;
        __syncthreads();
    }
    int base = (t == 0) ? 0 : part[t - 1];
    for (int i = lo; i < hi; ++i) {
        bbase[i] = base;
        base += btotal[i];
    }
    if (t == 0) offsets[N_NODES] = N_EDGES;
}

// K4: bscatter (blocks [0,256), starts first) ∥ proj second part (500 blk).
__global__ __launch_bounds__(256, 2) void k_projB_scatter(
    const float* __restrict__ x, const unsigned short* __restrict__ Wtg,
    const float* __restrict__ a_src, const float* __restrict__ a_dst,
    unsigned short* __restrict__ h_u16, float* __restrict__ attn_s4,
    float* __restrict__ attn_d4,
    const int* __restrict__ ei, const float* __restrict__ ew,
    const int* __restrict__ bhist, const int* __restrict__ bbase,
    uint2* __restrict__ brec64)
{
    __shared__ unsigned short xls[64 * WPITCH];    // 17408 B
    __shared__ unsigned short wls[128 * WPITCH];   // 34816 B
    __shared__ int cur[NBUCKET];                   // 6252 B
    const int t = threadIdx.x;

    if (blockIdx.x < BBLK) {
        // ---- scatter half ----
        const int blk = blockIdx.x;
        const int* row = bhist + (size_t)blk * NBUCKET;
        for (int i = t; i < NBUCKET; i += 256) cur[i] = bbase[i] + row[i];
        __syncthreads();
        const int* srcp = ei + blk * EPB;
        const int* dstp = ei + N_EDGES + blk * EPB;
        const float* wp = ew + blk * EPB;
        for (int i = t; i < EPB; i += 256) {
            const int src = srcp[i];
            const int dst = dstp[i];
            const float w = wp[i];
            const int pos = atomicAdd(&cur[dst >> 5], 1);
            brec64[pos] = make_uint2(((unsigned)src << 16) | (unsigned)f16_bits(w),
                                     (unsigned)(dst & 31));
        }
        return;
    }
    proj_body(blockIdx.x - BBLK + PROJ_A, t, xls, wls,
              x, Wtg, a_src, a_dst, h_u16, attn_s4, attn_d4);
}

// K5: within-bucket finish, single global read. Bucket segment -> LDS,
// LDS hist+scan+sort, coalesced 4 B rec write + offsets.
__global__ __launch_bounds__(256) void k_bfinish(
    const uint2* __restrict__ brec64, const int* __restrict__ bbase,
    const int* __restrict__ btotal,
    unsigned* __restrict__ rec, int* __restrict__ offsets)
{
    __shared__ uint2 stage[BCAP];                  // 16 KB
    __shared__ unsigned sorted[BCAP];              // 8 KB
    __shared__ int bin[32], bcur[32];
    const int j = blockIdx.x;
    const int t = threadIdx.x;
    const int start = bbase[j];
    const int n = btotal[j];

    if (t < 32) bin[t] = 0;
    __syncthreads();
    for (int i = t; i < n; i += 256) {
        const uint2 v = brec64[start + i];
        stage[i] = v;
        atomicAdd(&bin[v.y], 1);
    }
    __syncthreads();
    if (t == 0) {
        int run = 0;
        #pragma unroll
        for (int b = 0; b < 32; ++b) { bcur[b] = run; run += bin[b]; }
    }
    __syncthreads();
    if (t < 32) {
        const int d = j * 32 + t;
        if (d < N_NODES) offsets[d] = start + bcur[t];
    }
    __syncthreads();
    for (int i = t; i < n; i += 256) {
        const uint2 v = stage[i];
        sorted[atomicAdd(&bcur[v.y], 1)] = v.x;
    }
    __syncthreads();
    for (int i = t; i < n; i += 256) rec[start + i] = sorted[i];
}

// K6: per-dst gather-aggregate, 2x MLP: two 16-edge chunks per iteration,
// all 32 h-gathers issued before any FMA. Lane-parallel p-phase.
__global__ __launch_bounds__(256) void k_aggregate(
    const unsigned* __restrict__ rec, const int* __restrict__ offsets,
    const float* __restrict__ attn_s4, const float* __restrict__ attn_d4,
    const unsigned* __restrict__ h32, float* __restrict__ out)
{
    const int l = threadIdx.x & 63;
    const int le = l & 15;                         // edge slot
    const int lh = l >> 4;                         // head
    const int wid = blockIdx.x * 4 + (threadIdx.x >> 6);
    const unsigned* hp = h32 + l;

    for (int dst = wid; dst < N_NODES; dst += AGG_WAVES) {
        const int beg = offsets[dst];
        const int end = offsets[dst + 1];
        const float ad = attn_d4[dst * HEADS + lh];
        float dacc = 0.f;
        float a0 = 0.f, a1 = 0.f, b0 = 0.f, b1 = 0.f;
        int c = beg;
        // ---- main: 32 edges per iteration, 32 gathers in flight ----
        for (; c + 32 <= end; c += 32) {
            const unsigned uA = rec[c + le];
            const unsigned uB = rec[c + 16 + le];
            float loA = attn_s4[(uA >> 16) * HEADS + lh] + ad;
            float loB = attn_s4[(uB >> 16) * HEADS + lh] + ad;
            loA = ((loA >= 0.f) ? loA : NEG_SLOPE * loA) * f16u(uA & 0xffffu);
            loB = ((loB >= 0.f) ? loB : NEG_SLOPE * loB) * f16u(uB & 0xffffu);
            const unsigned pkA = (unsigned)f16_bits(__expf(loA));
            const unsigned pkB = (unsigned)f16_bits(__expf(loB));
            dacc += f16u((unsigned short)pkA) + f16u((unsigned short)pkB);
            unsigned hvA[16], hvB[16];
            #pragma unroll
            for (int q = 0; q < 16; ++q) {
                const unsigned uq = (unsigned)__shfl((int)uA, q, 16);
                hvA[q] = hp[(size_t)(uq >> 16) * 64];
            }
            #pragma unroll
            for (int q = 0; q < 16; ++q) {
                const unsigned uq = (unsigned)__shfl((int)uB, q, 16);
                hvB[q] = hp[(size_t)(uq >> 16) * 64];
            }
            #pragma unroll
            for (int q = 0; q < 16; q += 2) {
                const float p0 = f16u((unsigned short)__shfl((int)pkA, q, 16));
                const float p1 = f16u((unsigned short)__shfl((int)pkA, q + 1, 16));
                a0 = fmaf(p0, __uint_as_float(hvA[q] << 16), a0);
                b0 = fmaf(p0, __uint_as_float(hvA[q] & 0xffff0000u), b0);
                a1 = fmaf(p1, __uint_as_float(hvA[q + 1] << 16), a1);
                b1 = fmaf(p1, __uint_as_float(hvA[q + 1] & 0xffff0000u), b1);
            }
            #pragma unroll
            for (int q = 0; q < 16; q += 2) {
                const float p0 = f16u((unsigned short)__shfl((int)pkB, q, 16));
                const float p1 = f16u((unsigned short)__shfl((int)pkB, q + 1, 16));
                a0 = fmaf(p0, __uint_as_float(hvB[q] << 16), a0);
                b0 = fmaf(p0, __uint_as_float(hvB[q] & 0xffff0000u), b0);
                a1 = fmaf(p1, __uint_as_float(hvB[q + 1] << 16), a1);
                b1 = fmaf(p1, __uint_as_float(hvB[q + 1] & 0xffff0000u), b1);
            }
        }
        // ---- tail: 16-edge chunks ----
        for (; c < end; c += 16) {
            const int cnt = min(16, end - c);
            unsigned u = 0;
            float pr = 0.f;
            if (le < cnt) {
                u = rec[c + le];
                const int s = u >> 16;
                float lo = attn_s4[s * HEADS + lh] + ad;
                lo = ((lo >= 0.f) ? lo : NEG_SLOPE * lo) * f16u(u & 0xffffu);
                pr = __expf(lo);
            }
            const unsigned pk = (unsigned)f16_bits(pr);
            dacc += f16u((unsigned short)pk);
            for (int q = 0; q < cnt; ++q) {
                const unsigned uq = (unsigned)__shfl((int)u, q, 16);
                const float p0 = f16u((unsigned short)__shfl((int)pk, q, 16));
                const unsigned h0 = hp[(size_t)(uq >> 16) * 64];
                a0 = fmaf(p0, __uint_as_float(h0 << 16), a0);
                b0 = fmaf(p0, __uint_as_float(h0 & 0xffff0000u), b0);
            }
        }
        float den = dacc;
        #pragma unroll
        for (int m = 8; m >= 1; m >>= 1) den += __shfl_xor(den, m, 16);
        const float inv = 1.f / (den + 1e-10f);
        float2 o;
        o.x = (a0 + a1) * inv;
        o.y = (b0 + b1) * inv;
        ((float2*)out)[(size_t)dst * 64 + l] = o;
    }
}

extern "C" void kernel_launch(void* const* d_in, const int* in_sizes, int n_in,
                              void* d_out, int out_size, void* d_ws, size_t ws_size,
                              hipStream_t stream) {
    const float* x   = (const float*)d_in[0];
    const int*   ei  = (const int*)d_in[1];
    const float* ew  = (const float*)d_in[2];
    const float* W   = (const float*)d_in[3];
    const float* a_s = (const float*)d_in[4];
    const float* a_d = (const float*)d_in[5];
    float* out = (float*)d_out;

    unsigned* h32     = (unsigned*)d_ws;                          // 12.8 MB
    float*    attn_s4 = (float*)(h32 + (size_t)N_NODES * 64);     // 800 KB
    float*    attn_d4 = attn_s4 + (size_t)N_NODES * HEADS;        // 800 KB
    uint2*    brec64  = (uint2*)(attn_d4 + (size_t)N_NODES * HEADS); // 12.8 MB
    unsigned* rec     = (unsigned*)(brec64 + N_EDGES);            // 6.4 MB
    int*      bhist   = (int*)(rec + N_EDGES);                    // 1.6 MB
    int*      btotal  = bhist + BBLK * NBUCKET;                   // 6.3 KB
    int*      bbase   = btotal + NBUCKET;                         // 6.3 KB
    int*      offsets = bbase + NBUCKET;                          // 200 KB
    unsigned short* Wtg = (unsigned short*)(offsets + N_NODES + 1); // 35 KB

    k_bhist<<<BBLK + 8, 1024, 0, stream>>>(ei, bhist, W, Wtg);
    k_projA_scan<<<SCAN_BLKS + PROJ_A, 256, 0, stream>>>(
        x, Wtg, a_s, a_d, (unsigned short*)h32, attn_s4, attn_d4,
        bhist, btotal);
    k_bbase<<<1, 256, 0, stream>>>(btotal, bbase, offsets);
    k_projB_scatter<<<BBLK + PROJ_B, 256, 0, stream>>>(
        x, Wtg, a_s, a_d, (unsigned short*)h32, attn_s4, attn_d4,
        ei, ew, bhist, bbase, brec64);
    k_bfinish<<<NBUCKET, 256, 0, stream>>>(brec64, bbase, btotal, rec, offsets);
    k_aggregate<<<AGG_BLOCKS, 256, 0, stream>>>(rec, offsets, attn_s4,
                                                attn_d4, h32, out);
}

// Round 24
// 128.603 us; speedup vs baseline: 1.3001x; 1.3001x over previous
//
#include <hip/hip_runtime.h>
#include <hip/hip_bf16.h>
#include <hip/hip_fp16.h>

#define N_NODES 50000
#define N_EDGES 1600000
#define IN_F 128
#define OUT_F 32
#define HEADS 4
#define NEG_SLOPE 0.2f
#define HO (HEADS * OUT_F)

#define NBUCKET 1563                           // ceil(N_NODES / 32)
#define BBLK 256                               // histogram/scatter blocks
#define EPB (N_EDGES / BBLK)                   // 6250 edges per block
#define PROJ_BLOCKS ((N_NODES + 63) / 64)      // 782
#define PROJ_A 282                             // paired with colscan (~10us)
#define PROJ_B (PROJ_BLOCKS - PROJ_A)          // 500, paired with scatter
#define SCAN_BLKS ((NBUCKET + 255) / 256)      // 7
#define AGG_BLOCKS 3125
#define AGG_WAVES (AGG_BLOCKS * 4)
#define WPITCH 136                             // bf16 pitch (17 x b128)
#define BCAP 2048                              // max records per bucket (LDS)

typedef __attribute__((ext_vector_type(8))) short bf16x8;
typedef __attribute__((ext_vector_type(4))) float f32x4;

__device__ __forceinline__ unsigned short bf16_bits(float f) {
    union { __hip_bfloat16 b; unsigned short u; } cv;
    cv.b = __float2bfloat16(f);
    return cv.u;
}
__device__ __forceinline__ unsigned short f16_bits(float f) {
    union { __half h; unsigned short u; } cv;
    cv.h = __float2half(f);
    return cv.u;
}
__device__ __forceinline__ float f16u(unsigned short u) {
    union { unsigned short x; __half h; } cv;
    cv.x = u;
    return __half2float(cv.h);
}

// ---- shared proj body (node tile pb: 64 nodes x 128 cols, K=128) ----
__device__ __forceinline__ void proj_body(
    int pb, int t, unsigned short* xls, unsigned short* wls,
    const float* __restrict__ x, const unsigned short* __restrict__ Wtg,
    const float* __restrict__ a_src, const float* __restrict__ a_dst,
    unsigned short* __restrict__ h_u16, float* __restrict__ attn_s4,
    float* __restrict__ attn_d4)
{
    const int base = pb * 64;
    {   // stage Wt (flat copy, already padded): 2176 uint4
        const uint4* src = (const uint4*)Wtg;
        uint4* dst = (uint4*)wls;
        for (int i = t; i < 2176; i += 256) dst[i] = src[i];
    }
    {   // stage x tile: 64 rows x 32 float4, convert to bf16
        const float4* xsrc = (const float4*)x + (size_t)base * 32;
        #pragma unroll
        for (int i = 0; i < 8; ++i) {
            const int idx = t + i * 256;           // 0..2047
            const int row = idx >> 5;
            const int c4 = idx & 31;
            float4 v = {0.f, 0.f, 0.f, 0.f};
            if (base + row < N_NODES) v = xsrc[row * 32 + c4];
            ushort4 o;
            o.x = bf16_bits(v.x); o.y = bf16_bits(v.y);
            o.z = bf16_bits(v.z); o.w = bf16_bits(v.w);
            *(ushort4*)&xls[row * WPITCH + c4 * 4] = o;
        }
    }
    __syncthreads();

    const int w = t >> 6;                          // m-tile 0..3
    const int lane = t & 63;
    const int lr = lane & 15;                      // A-row / B-col
    const int lq = lane >> 4;                      // k-quadrant

    const unsigned short* ap = &xls[(w * 16 + lr) * WPITCH + lq * 8];
    const unsigned short* bp = &wls[lr * WPITCH + lq * 8];

    f32x4 acc[8];
    #pragma unroll
    for (int ct = 0; ct < 8; ++ct) acc[ct] = (f32x4){0.f, 0.f, 0.f, 0.f};

    #pragma unroll
    for (int ks = 0; ks < 4; ++ks) {
        const bf16x8 a = *(const bf16x8*)(ap + ks * 32);
        #pragma unroll
        for (int ct = 0; ct < 8; ++ct) {
            const bf16x8 bv = *(const bf16x8*)(bp + ct * 16 * WPITCH + ks * 32);
            acc[ct] = __builtin_amdgcn_mfma_f32_16x16x32_bf16(a, bv, acc[ct], 0, 0, 0);
        }
    }

    const int nodeq = base + w * 16 + lq * 4;
    #pragma unroll
    for (int r = 0; r < 4; ++r) {
        const int node = nodeq + r;
        if (node >= N_NODES) continue;
        unsigned short* hrow = h_u16 + (size_t)node * 128 + lr;
        #pragma unroll
        for (int ct = 0; ct < 8; ++ct)
            hrow[ct * 16] = bf16_bits(acc[ct][r]);
    }

    float asv[8], adv[8];
    #pragma unroll
    for (int h = 0; h < 4; ++h) {
        asv[2 * h]     = a_src[32 * h + lr];
        asv[2 * h + 1] = a_src[32 * h + 16 + lr];
        adv[2 * h]     = a_dst[32 * h + lr];
        adv[2 * h + 1] = a_dst[32 * h + 16 + lr];
    }
    #pragma unroll
    for (int h = 0; h < 4; ++h) {
        #pragma unroll
        for (int r = 0; r < 4; ++r) {
            float ps = acc[2 * h][r] * asv[2 * h] + acc[2 * h + 1][r] * asv[2 * h + 1];
            float pd = acc[2 * h][r] * adv[2 * h] + acc[2 * h + 1][r] * adv[2 * h + 1];
            #pragma unroll
            for (int m = 8; m >= 1; m >>= 1) {
                ps += __shfl_xor(ps, m);
                pd += __shfl_xor(pd, m);
            }
            const int node = nodeq + r;
            if (lr == 0 && node < N_NODES) {
                attn_s4[node * HEADS + h] = ps;
                attn_d4[node * HEADS + h] = pd;
            }
        }
    }
}

// K1: blocks [0,256): per-block LDS histogram over 1563 coarse buckets
//     (dst>>5), 1024 threads. blocks [256,264): W -> Wtg bf16 transpose.
__global__ __launch_bounds__(1024) void k_bhist(
    const int* __restrict__ ei, int* __restrict__ bhist,
    const float* __restrict__ W, unsigned short* __restrict__ Wtg)
{
    const int blk = blockIdx.x;
    const int t = threadIdx.x;
    if (blk >= BBLK) {                          // W prep
        const int bp = blk - BBLK;
        #pragma unroll
        for (int i = 0; i < 2; ++i) {
            const int idx = bp * 2048 + t + i * 1024;  // 16384 f32 total
            const int h = idx >> 12;
            const int k = (idx >> 5) & 127;
            const int o = idx & 31;
            Wtg[(size_t)(h * 32 + o) * WPITCH + k] = bf16_bits(W[idx]);
        }
        return;
    }
    __shared__ int lhist[NBUCKET];
    for (int i = t; i < NBUCKET; i += 1024) lhist[i] = 0;
    __syncthreads();
    const int* dstp = ei + N_EDGES + blk * EPB;
    for (int i = t; i < EPB; i += 1024)
        atomicAdd(&lhist[dstp[i] >> 5], 1);
    __syncthreads();
    int* dump = bhist + (size_t)blk * NBUCKET;
    for (int i = t; i < NBUCKET; i += 1024) dump[i] = lhist[i];
}

// K2: proj first part (nodes [0, 282*64)) ∥ bhist column-scan.
__global__ __launch_bounds__(256, 2) void k_projA_scan(
    const float* __restrict__ x, const unsigned short* __restrict__ Wtg,
    const float* __restrict__ a_src, const float* __restrict__ a_dst,
    unsigned short* __restrict__ h_u16, float* __restrict__ attn_s4,
    float* __restrict__ attn_d4, int* __restrict__ bhist,
    int* __restrict__ btotal)
{
    __shared__ unsigned short xls[64 * WPITCH];    // 17408 B
    __shared__ unsigned short wls[128 * WPITCH];   // 34816 B
    const int t = threadIdx.x;

    if (blockIdx.x < SCAN_BLKS) {
        const int j = blockIdx.x * 256 + t;
        if (j >= NBUCKET) return;
        int run = 0;
        for (int blk = 0; blk < BBLK; blk += 8) {
            int v[8];
            #pragma unroll
            for (int q = 0; q < 8; ++q)
                v[q] = bhist[(size_t)(blk + q) * NBUCKET + j];
            #pragma unroll
            for (int q = 0; q < 8; ++q) {
                const int nv = v[q];
                bhist[(size_t)(blk + q) * NBUCKET + j] = run;
                run += nv;
            }
        }
        btotal[j] = run;
        return;
    }
    proj_body(blockIdx.x - SCAN_BLKS, t, xls, wls,
              x, Wtg, a_src, a_dst, h_u16, attn_s4, attn_d4);
}

// K3: exclusive scan of bucket totals -> bbase (single block)
__global__ __launch_bounds__(256) void k_bbase(
    const int* __restrict__ btotal, int* __restrict__ bbase,
    int* __restrict__ offsets)
{
    __shared__ int part[256];
    const int t = threadIdx.x;
    const int CH = 7;                              // 7*256 >= 1563
    const int lo = t * CH;
    const int hi = min(lo + CH, NBUCKET);
    int s = 0;
    for (int i = lo; i < hi; ++i) s += btotal[i];
    part[t] = s;
    __syncthreads();
    for (int d = 1; d < 256; d <<= 1) {
        const int v = (t >= d) ? part[t - d] : 0;
        __syncthreads();
        part[t] += v;
        __syncthreads();
    }
    int base = (t == 0) ? 0 : part[t - 1];
    for (int i = lo; i < hi; ++i) {
        bbase[i] = base;
        base += btotal[i];
    }
    if (t == 0) offsets[N_NODES] = N_EDGES;
}

// K4: bscatter (blocks [0,256), starts first) ∥ proj second part (500 blk).
__global__ __launch_bounds__(256, 2) void k_projB_scatter(
    const float* __restrict__ x, const unsigned short* __restrict__ Wtg,
    const float* __restrict__ a_src, const float* __restrict__ a_dst,
    unsigned short* __restrict__ h_u16, float* __restrict__ attn_s4,
    float* __restrict__ attn_d4,
    const int* __restrict__ ei, const float* __restrict__ ew,
    const int* __restrict__ bhist, const int* __restrict__ bbase,
    uint2* __restrict__ brec64)
{
    __shared__ unsigned short xls[64 * WPITCH];    // 17408 B
    __shared__ unsigned short wls[128 * WPITCH];   // 34816 B
    __shared__ int cur[NBUCKET];                   // 6252 B
    const int t = threadIdx.x;

    if (blockIdx.x < BBLK) {
        // ---- scatter half ----
        const int blk = blockIdx.x;
        const int* row = bhist + (size_t)blk * NBUCKET;
        for (int i = t; i < NBUCKET; i += 256) cur[i] = bbase[i] + row[i];
        __syncthreads();
        const int* srcp = ei + blk * EPB;
        const int* dstp = ei + N_EDGES + blk * EPB;
        const float* wp = ew + blk * EPB;
        for (int i = t; i < EPB; i += 256) {
            const int src = srcp[i];
            const int dst = dstp[i];
            const float w = wp[i];
            const int pos = atomicAdd(&cur[dst >> 5], 1);
            brec64[pos] = make_uint2(((unsigned)src << 16) | (unsigned)f16_bits(w),
                                     (unsigned)(dst & 31));
        }
        return;
    }
    proj_body(blockIdx.x - BBLK + PROJ_A, t, xls, wls,
              x, Wtg, a_src, a_dst, h_u16, attn_s4, attn_d4);
}

// K5: within-bucket finish, single global read. Bucket segment -> LDS,
// LDS hist+scan+sort, coalesced 4 B rec write + offsets.
__global__ __launch_bounds__(256) void k_bfinish(
    const uint2* __restrict__ brec64, const int* __restrict__ bbase,
    const int* __restrict__ btotal,
    unsigned* __restrict__ rec, int* __restrict__ offsets)
{
    __shared__ uint2 stage[BCAP];                  // 16 KB
    __shared__ unsigned sorted[BCAP];              // 8 KB
    __shared__ int bin[32], bcur[32];
    const int j = blockIdx.x;
    const int t = threadIdx.x;
    const int start = bbase[j];
    const int n = btotal[j];

    if (t < 32) bin[t] = 0;
    __syncthreads();
    for (int i = t; i < n; i += 256) {
        const uint2 v = brec64[start + i];
        stage[i] = v;
        atomicAdd(&bin[v.y], 1);
    }
    __syncthreads();
    if (t == 0) {
        int run = 0;
        #pragma unroll
        for (int b = 0; b < 32; ++b) { bcur[b] = run; run += bin[b]; }
    }
    __syncthreads();
    if (t < 32) {
        const int d = j * 32 + t;
        if (d < N_NODES) offsets[d] = start + bcur[t];
    }
    __syncthreads();
    for (int i = t; i < n; i += 256) {
        const uint2 v = stage[i];
        sorted[atomicAdd(&bcur[v.y], 1)] = v.x;
    }
    __syncthreads();
    for (int i = t; i < n; i += 256) rec[start + i] = sorted[i];
}

// K6: per-dst gather-aggregate (verified best: ~69.5 us). Lane-parallel
// p-phase, decoupled gathers, compiler-pipelined 16-edge chunks.
__global__ __launch_bounds__(256) void k_aggregate(
    const unsigned* __restrict__ rec, const int* __restrict__ offsets,
    const float* __restrict__ attn_s4, const float* __restrict__ attn_d4,
    const unsigned* __restrict__ h32, float* __restrict__ out)
{
    const int l = threadIdx.x & 63;
    const int le = l & 15;                         // edge slot
    const int lh = l >> 4;                         // head
    const int wid = blockIdx.x * 4 + (threadIdx.x >> 6);
    const unsigned* hp = h32 + l;

    for (int dst = wid; dst < N_NODES; dst += AGG_WAVES) {
        const int beg = offsets[dst];
        const int end = offsets[dst + 1];
        const float ad = attn_d4[dst * HEADS + lh];
        float dacc = 0.f;
        float a0 = 0.f, a1 = 0.f, b0 = 0.f, b1 = 0.f;
        for (int c = beg; c < end; c += 16) {
            const int cnt = min(16, end - c);
            unsigned u = 0;
            float pr = 0.f;
            if (le < cnt) {
                u = rec[c + le];
                const int s = u >> 16;
                float lo = attn_s4[s * HEADS + lh] + ad;
                lo = ((lo >= 0.f) ? lo : NEG_SLOPE * lo) * f16u(u & 0xffffu);
                pr = __expf(lo);
            }
            const unsigned pk = (unsigned)f16_bits(pr);
            dacc += f16u((unsigned short)pk);
            if (cnt == 16) {
                unsigned hv[16];
                #pragma unroll
                for (int q = 0; q < 16; ++q) {
                    const unsigned uq = (unsigned)__shfl((int)u, q, 16);
                    hv[q] = hp[(size_t)(uq >> 16) * 64];
                }
                #pragma unroll
                for (int q = 0; q < 16; q += 2) {
                    const float p0 = f16u((unsigned short)__shfl((int)pk, q, 16));
                    const float p1 = f16u((unsigned short)__shfl((int)pk, q + 1, 16));
                    a0 = fmaf(p0, __uint_as_float(hv[q] << 16), a0);
                    b0 = fmaf(p0, __uint_as_float(hv[q] & 0xffff0000u), b0);
                    a1 = fmaf(p1, __uint_as_float(hv[q + 1] << 16), a1);
                    b1 = fmaf(p1, __uint_as_float(hv[q + 1] & 0xffff0000u), b1);
                }
            } else {
                for (int q = 0; q < cnt; ++q) {
                    const unsigned uq = (unsigned)__shfl((int)u, q, 16);
                    const float p0 = f16u((unsigned short)__shfl((int)pk, q, 16));
                    const unsigned h0 = hp[(size_t)(uq >> 16) * 64];
                    a0 = fmaf(p0, __uint_as_float(h0 << 16), a0);
                    b0 = fmaf(p0, __uint_as_float(h0 & 0xffff0000u), b0);
                }
            }
        }
        float den = dacc;
        #pragma unroll
        for (int m = 8; m >= 1; m >>= 1) den += __shfl_xor(den, m, 16);
        const float inv = 1.f / (den + 1e-10f);
        float2 o;
        o.x = (a0 + a1) * inv;
        o.y = (b0 + b1) * inv;
        ((float2*)out)[(size_t)dst * 64 + l] = o;
    }
}

extern "C" void kernel_launch(void* const* d_in, const int* in_sizes, int n_in,
                              void* d_out, int out_size, void* d_ws, size_t ws_size,
                              hipStream_t stream) {
    const float* x   = (const float*)d_in[0];
    const int*   ei  = (const int*)d_in[1];
    const float* ew  = (const float*)d_in[2];
    const float* W   = (const float*)d_in[3];
    const float* a_s = (const float*)d_in[4];
    const float* a_d = (const float*)d_in[5];
    float* out = (float*)d_out;

    unsigned* h32     = (unsigned*)d_ws;                          // 12.8 MB
    float*    attn_s4 = (float*)(h32 + (size_t)N_NODES * 64);     // 800 KB
    float*    attn_d4 = attn_s4 + (size_t)N_NODES * HEADS;        // 800 KB
    uint2*    brec64  = (uint2*)(attn_d4 + (size_t)N_NODES * HEADS); // 12.8 MB
    unsigned* rec     = (unsigned*)(brec64 + N_EDGES);            // 6.4 MB
    int*      bhist   = (int*)(rec + N_EDGES);                    // 1.6 MB
    int*      btotal  = bhist + BBLK * NBUCKET;                   // 6.3 KB
    int*      bbase   = btotal + NBUCKET;                         // 6.3 KB
    int*      offsets = bbase + NBUCKET;                          // 200 KB
    unsigned short* Wtg = (unsigned short*)(offsets + N_NODES + 1); // 35 KB

    k_bhist<<<BBLK + 8, 1024, 0, stream>>>(ei, bhist, W, Wtg);
    k_projA_scan<<<SCAN_BLKS + PROJ_A, 256, 0, stream>>>(
        x, Wtg, a_s, a_d, (unsigned short*)h32, attn_s4, attn_d4,
        bhist, btotal);
    k_bbase<<<1, 256, 0, stream>>>(btotal, bbase, offsets);
    k_projB_scatter<<<BBLK + PROJ_B, 256, 0, stream>>>(
        x, Wtg, a_s, a_d, (unsigned short*)h32, attn_s4, attn_d4,
        ei, ew, bhist, bbase, brec64);
    k_bfinish<<<NBUCKET, 256, 0, stream>>>(brec64, bbase, btotal, rec, offsets);
    k_aggregate<<<AGG_BLOCKS, 256, 0, stream>>>(rec, offsets, attn_s4,
                                                attn_d4, h32, out);
}